// Round 5
// baseline (57.492 us; speedup 1.0000x reference)
//
#include <hip/hip_runtime.h>
#include <math.h>

#define NBQ 50
#define S1 51
#define NPTS 2601      // 51*51
#define NTILES 163     // ceil(2601/16)
#define IN_D 64
#define HID 128
#define BSZ 256
#define NCHUNK 8

typedef __bf16 bf16x8 __attribute__((ext_vector_type(8)));
typedef float  f32x4  __attribute__((ext_vector_type(4)));

// ws layout (floats)
#define WS_CC     0                    // 51
#define WS_STEPS  64                   // 51
#define WS_XMAX   128                  // 1
#define WS_BASE   256                  // 256*128 = 32768
#define WS_SCAL   33024                // 256
#define WS_OFF    33280                // 256
#define WS_PART   33536                // 2048 (256 b * 8 chunks)
#define WS_W1BF   35840                // 16384 bf16 = 8192 floats

// ---------------- prep: w1 fragment conversion + cc/steps/xmax + base + n-net
__global__ void k_prep(const float* __restrict__ x, const float* __restrict__ h,
                       const float* __restrict__ iw0, const float* __restrict__ ib0,
                       const float* __restrict__ iw1,
                       const float* __restrict__ nw0, const float* __restrict__ nb0,
                       const float* __restrict__ nw1, const float* __restrict__ nb1,
                       const float* __restrict__ nw2, const float* __restrict__ nb2,
                       float* __restrict__ ws) {
    int blk = blockIdx.x;
    int tid = threadIdx.x;

    if (blk < 64) {
        // A-frag order: idx = ((NT*4+kk)*64 + lane)*8 + e
        //  value = iw1[(kk*32 + (lane>>4)*8 + e)*128 + NT*16 + (lane&15)]
        int idx  = blk * 256 + tid;      // 0..16383
        int e    = idx & 7;
        int lane = (idx >> 3) & 63;
        int fk   = idx >> 9;             // 0..31
        int kk   = fk & 3;
        int nt   = fk >> 2;
        int k = kk * 32 + (lane >> 4) * 8 + e;
        int n = nt * 16 + (lane & 15);
        __bf16* w1bf = (__bf16*)(ws + WS_W1BF);
        w1bf[idx] = (__bf16)iw1[k * HID + n];
        return;
    }

    __shared__ float s_steps[S1];
    __shared__ float s_red[4];
    __shared__ float s_h[IN_D - 1];
    __shared__ float s_o0[HID];
    __shared__ float s_part[4];

    if (blk == 64) {
        int t = tid;
        if (t < S1) {
            double st = cos((double)t * M_PI / (double)NBQ);
            s_steps[t] = (float)st;
            ws[WS_STEPS + t] = (float)st;
            double acc = 0.0;
            for (int i = 0; i <= NBQ; ++i) {
                double Wi;
                if (i == 0)       Wi = 1.0;
                else if (i & 1)   Wi = 0.0;
                else              Wi = 2.0 / (1.0 - (double)i * (double)i);
                double lam;
                if (t == 0)  lam = 0.5;
                else         lam = cos((double)i * (double)t * M_PI / (double)NBQ);
                if (t == NBQ) lam *= 0.5;
                lam *= 2.0 / (double)NBQ;
                acc += lam * Wi;
            }
            ws[WS_CC + t] = (float)acc;
        }
        __syncthreads();
        float xb = x[t];
        float m = -1e30f;
        for (int i = 0; i < S1; ++i)
            m = fmaxf(m, xb * (s_steps[i] + 1.0f) * 0.5f);
        for (int off = 32; off > 0; off >>= 1)
            m = fmaxf(m, __shfl_down(m, off));
        if ((t & 63) == 0) s_red[t >> 6] = m;
        __syncthreads();
        if (t == 0) {
            float mm = fmaxf(fmaxf(s_red[0], s_red[1]), fmaxf(s_red[2], s_red[3]));
            ws[WS_XMAX] = mm + 10.0f;
        }
        return;
    }

    // ---- base[b] + n-network: b = blk - 65, first 128 threads active ----
    int b = blk - 65;
    int n = tid;
    bool act = (n < HID);
    if (act && n < IN_D - 1) s_h[n] = h[b * (IN_D - 1) + n];
    __syncthreads();
    float o1 = 0.0f;
    if (act) {
        float accB = ib0[n];
        float acc0 = nb0[n];
        for (int d = 0; d < IN_D - 1; ++d) {
            float hv = s_h[d];
            accB = fmaf(hv, iw0[(1 + d) * HID + n], accB);
            acc0 = fmaf(hv, nw0[d * HID + n], acc0);
        }
        ws[WS_BASE + b * HID + n] = accB;
        s_o0[n] = fmaxf(acc0, 0.0f);
    }
    __syncthreads();
    if (act) {
        float acc1 = nb1[n];
        for (int m = 0; m < HID; ++m)
            acc1 = fmaf(s_o0[m], nw1[m * HID + n], acc1);
        o1 = fmaxf(acc1, 0.0f);
    }
    float p0 = act ? o1 * nw2[n * 2 + 0] : 0.0f;
    float p1 = act ? o1 * nw2[n * 2 + 1] : 0.0f;
    for (int off = 32; off > 0; off >>= 1) {
        p0 += __shfl_down(p0, off);
        p1 += __shfl_down(p1, off);
    }
    int lane = tid & 63, w = tid >> 6;
    if (lane == 0 && w < 2) { s_part[w * 2] = p0; s_part[w * 2 + 1] = p1; }
    __syncthreads();
    if (tid == 0) {
        ws[WS_OFF + b]  = s_part[0] + s_part[2] + nb2[0];
        ws[WS_SCAL + b] = expf(s_part[1] + s_part[3] + nb2[1]);
    }
}

// ---------------- main MFMA kernel: n-split across 2 waves for 2x occupancy --
// Block = 128 threads (2 waves). Wave w owns n-tiles NT = w*4 .. w*4+3.
// Both waves build the same per-point a0 fragments; each does half the MFMAs
// and half the layer-2 contraction; z-halves combined via LDS (1 barrier/tile).
__global__ __launch_bounds__(128, 2) void k3_mfma(
        const float* __restrict__ x,
        const float* __restrict__ iw0,   // row 0 = w0 (128 floats)
        const float* __restrict__ ib1,
        const float* __restrict__ iw2,
        const float* __restrict__ ib2,
        float* __restrict__ ws) {
    __shared__ float s_cc[S1];
    __shared__ float s_ti[S1];
    __shared__ float s_w[S1];
    __shared__ float s_sjh[S1];
    __shared__ float s_ccw[S1];
    __shared__ float s_z[2][16];

    int blk  = blockIdx.x;
    int b    = blk >> 3;
    int c    = blk & 7;
    int tid  = threadIdx.x;
    int wave = tid >> 6;             // 0 or 1
    int lane = tid & 63;
    int col  = lane & 15;
    int g    = lane >> 4;            // 0..3

    float xmax = ws[WS_XMAX];
    float xb   = x[b];
    float b2   = ib2[0];

    if (tid < S1) {
        float st = ws[WS_STEPS + tid];
        float cc = ws[WS_CC + tid];
        float ti = xb * (st + 1.0f) * 0.5f;
        float w  = xmax - ti;
        s_cc[tid]  = cc;
        s_ti[tid]  = ti;
        s_w[tid]   = w;
        s_sjh[tid] = (st + 1.0f) * 0.5f;
        s_ccw[tid] = cc * w;
    }

    // W1 A-fragments for this wave's 4 n-tiles: 64 regs
    const bf16x8* w1f = (const bf16x8*)(ws + WS_W1BF);
    bf16x8 Af[4][4];
#pragma unroll
    for (int nt = 0; nt < 4; ++nt) {
        int NT = wave * 4 + nt;
#pragma unroll
        for (int kk = 0; kk < 4; ++kk)
            Af[nt][kk] = w1f[(NT * 4 + kk) * 64 + lane];
    }

    // per-lane w0/base for m = kk*32 + g*8 + e : 64 regs (full k-range)
    const float* basep = ws + WS_BASE + b * HID;
    f32x4 w0a[4], w0b[4], bsa[4], bsb[4];
#pragma unroll
    for (int kk = 0; kk < 4; ++kk) {
        int m0 = kk * 32 + g * 8;
        w0a[kk] = *(const f32x4*)(iw0 + m0);
        w0b[kk] = *(const f32x4*)(iw0 + m0 + 4);
        bsa[kk] = *(const f32x4*)(basep + m0);
        bsb[kk] = *(const f32x4*)(basep + m0 + 4);
    }

    // ib1 (MFMA C-init) and iw2 for this wave's n = NT*16 + g*4 + q : 32 regs
    f32x4 accInit[4], iw2v[4];
#pragma unroll
    for (int nt = 0; nt < 4; ++nt) {
        int n0 = (wave * 4 + nt) * 16 + g * 4;
        accInit[nt] = *(const f32x4*)(ib1 + n0);
        iw2v[nt]    = *(const f32x4*)(iw2 + n0);
    }

    __syncthreads();

    float vsum = 0.0f;
    int par = 0;

    for (int t = c; t < NTILES; t += NCHUNK) {
        int p  = t * 16 + col;
        int pc = (p < NPTS) ? p : (NPTS - 1);
        int i  = (int)(((unsigned)pc * 10281u) >> 19);   // pc / 51
        int j  = pc - i * 51;
        float s = fmaf(s_w[i], s_sjh[j], s_ti[i]);

        f32x4 acc[4];
#pragma unroll
        for (int kk = 0; kk < 4; ++kk) {
            bf16x8 bfr;
#pragma unroll
            for (int e = 0; e < 4; ++e) {
                bfr[e]     = (__bf16)fmaxf(fmaf(s, w0a[kk][e], bsa[kk][e]), 0.0f);
                bfr[4 + e] = (__bf16)fmaxf(fmaf(s, w0b[kk][e], bsb[kk][e]), 0.0f);
            }
#pragma unroll
            for (int nt = 0; nt < 4; ++nt)
                acc[nt] = __builtin_amdgcn_mfma_f32_16x16x32_bf16(
                    Af[nt][kk], bfr, (kk == 0) ? accInit[nt] : acc[nt], 0, 0, 0);
        }

        // layer2 partial over this wave's 64 n-values (16 per lane)
        float z = 0.0f;
#pragma unroll
        for (int nt = 0; nt < 4; ++nt)
#pragma unroll
            for (int q = 0; q < 4; ++q)
                z = fmaf(fmaxf(acc[nt][q], 0.0f), iw2v[nt][q], z);
        z += __shfl_xor(z, 16);
        z += __shfl_xor(z, 32);   // z = this wave's half-sum, in all lanes

        if (wave == 0 && g == 0) s_z[par][col] = z;
        __syncthreads();
        if (wave == 1) {
            float zf = z + s_z[par][col] + b2;
            float f  = (zf > 0.0f) ? (zf + 1.0f) : __expf(zf);
            float val = s_ccw[i] * s_cc[j] * f;
            vsum += (p < NPTS) ? val : 0.0f;
        }
        par ^= 1;
    }

    if (wave == 1) {
        // each point counted 4x (g) -> x0.25; inner weight /2 -> x0.125
#pragma unroll
        for (int off = 1; off < 64; off <<= 1)
            vsum += __shfl_xor(vsum, off);
        if (lane == 0)
            ws[WS_PART + blk] = vsum * 0.125f;
    }
}

// ---------------- final: out[b] = scal*(sum parts)*x/2 + off ----------------
__global__ void k4_final(const float* __restrict__ x, const float* __restrict__ ws,
                         float* __restrict__ out) {
    int b = threadIdx.x;
    float sum = 0.0f;
#pragma unroll
    for (int c = 0; c < NCHUNK; ++c) sum += ws[WS_PART + b * NCHUNK + c];
    out[b] = ws[WS_SCAL + b] * sum * x[b] * 0.5f + ws[WS_OFF + b];
}

extern "C" void kernel_launch(void* const* d_in, const int* in_sizes, int n_in,
                              void* d_out, int out_size, void* d_ws, size_t ws_size,
                              hipStream_t stream) {
    const float* x   = (const float*)d_in[0];
    const float* h   = (const float*)d_in[1];
    const float* iw0 = (const float*)d_in[2];
    const float* ib0 = (const float*)d_in[3];
    const float* iw1 = (const float*)d_in[4];
    const float* ib1 = (const float*)d_in[5];
    const float* iw2 = (const float*)d_in[6];
    const float* ib2 = (const float*)d_in[7];
    const float* nw0 = (const float*)d_in[8];
    const float* nb0 = (const float*)d_in[9];
    const float* nw1 = (const float*)d_in[10];
    const float* nb1 = (const float*)d_in[11];
    const float* nw2 = (const float*)d_in[12];
    const float* nb2 = (const float*)d_in[13];
    float* ws  = (float*)d_ws;
    float* out = (float*)d_out;

    hipLaunchKernelGGL(k_prep, dim3(64 + 1 + BSZ), dim3(256), 0, stream,
                       x, h, iw0, ib0, iw1, nw0, nb0, nw1, nb1, nw2, nb2, ws);
    hipLaunchKernelGGL(k3_mfma, dim3(BSZ * NCHUNK), dim3(128), 0, stream,
                       x, iw0, ib1, iw2, ib2, ws);
    hipLaunchKernelGGL(k4_final, dim3(1), dim3(BSZ), 0, stream, x, ws, out);
}